// Round 4
// baseline (2305.768 us; speedup 1.0000x reference)
//
#include <hip/hip_runtime.h>
#include <math.h>

typedef unsigned short ushort_t;
typedef __attribute__((ext_vector_type(8))) short short8;
typedef __attribute__((ext_vector_type(4))) short short4_t;
typedef __attribute__((ext_vector_type(4))) float f32x4;

#define MFMA_BF16(a,b,c) __builtin_amdgcn_mfma_f32_16x16x32_bf16((a),(b),(c),0,0,0)

__device__ __forceinline__ ushort_t f2bf(float f){
  union { float f; unsigned int i; } v; v.f = f;
  unsigned int r = v.i + 0x7fffu + ((v.i >> 16) & 1u);
  return (ushort_t)(r >> 16);
}
__device__ __forceinline__ float gelu_f(float x){
  return 0.5f * x * (1.0f + erff(x * 0.70710678118654752f));
}
// load 8 consecutive f32, convert to 8 bf16 (short8)
__device__ __forceinline__ short8 cvt8(const float* __restrict__ p){
  f32x4 a = *(const f32x4*)p;
  f32x4 b = *(const f32x4*)(p + 4);
  short8 t;
#pragma unroll
  for (int j = 0; j < 4; ++j) { t[j] = (short)f2bf(a[j]); t[4 + j] = (short)f2bf(b[j]); }
  return t;
}

// ---------------------------------------------------------------- prep: CSR
__global__ void k_prep(const int* __restrict__ e0, const int* __restrict__ pos,
                       int m, int* __restrict__ startp, int* __restrict__ degp){
  int i = blockIdx.x * 256 + threadIdx.x;
  if (i >= m) return;
  int s = e0[i];
  if (pos[i] == 0) startp[s] = i;
  if (i == m - 1 || e0[i + 1] != s) degp[s] = pos[i] + 1;
}

// ================================================================ FUSED
// One block per node: edge-MLP -> QKV -> attention -> Wo -> group softmax ->
// atomic scatter into f32 d_out. All global f32; LDS/MFMA in bf16.
__global__ __launch_bounds__(256, 1) void k_fused(
    const float* __restrict__ x,
    const float* __restrict__ Wc, const float* __restrict__ bc,
    const float* __restrict__ Wq, const float* __restrict__ bq,
    const float* __restrict__ Wk, const float* __restrict__ bk,
    const float* __restrict__ Wv, const float* __restrict__ bv,
    const float* __restrict__ Wo, const float* __restrict__ bo,
    const int* __restrict__ e1,
    const int* __restrict__ startp, const int* __restrict__ degp,
    float* __restrict__ dout, int m)
{
  __shared__ __align__(16) ushort_t sW[256 * 40];   // weight k-slab [col][40 pad]
  __shared__ __align__(16) ushort_t sX[32 * 288];   // ex tile [row][288]; P overlays
  __shared__ __align__(16) ushort_t sQ[32 * 264];   // q tile [row][264]; O overlays
  __shared__ __align__(16) ushort_t sK[32 * 264];   // k tile
  __shared__ __align__(16) ushort_t sVT[256 * 36];  // v^T [feature][36 pad key]

  const int node = blockIdx.x;
  const int st = startp[node], dg = degp[node];
  if (dg <= 0) return;
  const int tid = threadIdx.x;
  const int w = tid >> 6, lane = tid & 63;
  const int g = lane >> 4, li = lane & 15;

  // -------- phase 1: ex = gelu([x_src | x_dst] Wc^T + bc) -> sX
  int dstn[2];
#pragma unroll
  for (int mt = 0; mt < 2; ++mt)
    dstn[mt] = e1[min(st + mt * 16 + li, m - 1)];
  {
    f32x4 acc[2][4];
#pragma unroll
    for (int a = 0; a < 2; ++a)
#pragma unroll
      for (int b = 0; b < 4; ++b) acc[a][b] = (f32x4){0.f,0.f,0.f,0.f};
    for (int ks = 0; ks < 8; ++ks) {
      { const float* wr = Wc + (size_t)tid * 256 + ks * 32;
        short8 w0 = cvt8(wr), w1 = cvt8(wr+8), w2 = cvt8(wr+16), w3 = cvt8(wr+24);
        ushort_t* d = &sW[tid * 40];
        *(short8*)d = w0; *(short8*)(d+8) = w1; *(short8*)(d+16) = w2; *(short8*)(d+24) = w3; }
      __syncthreads();
      int k0 = ks * 32 + g * 8;
      short8 af[2];
#pragma unroll
      for (int mt = 0; mt < 2; ++mt) {
        const float* src = (k0 < 128) ? (x + (size_t)node * 128 + k0)
                                      : (x + (size_t)dstn[mt] * 128 + (k0 - 128));
        af[mt] = cvt8(src);
      }
#pragma unroll
      for (int nf = 0; nf < 4; ++nf) {
        short8 bf = *(const short8*)&sW[(w * 64 + nf * 16 + li) * 40 + g * 8];
#pragma unroll
        for (int mt = 0; mt < 2; ++mt) acc[mt][nf] = MFMA_BF16(af[mt], bf, acc[mt][nf]);
      }
      __syncthreads();
    }
#pragma unroll
    for (int nf = 0; nf < 4; ++nf) {
      int col = w * 64 + nf * 16 + li;
      float b = bc[col];
#pragma unroll
      for (int mt = 0; mt < 2; ++mt)
#pragma unroll
        for (int r = 0; r < 4; ++r)
          sX[(mt * 16 + g * 4 + r) * 288 + col] = f2bf(gelu_f(acc[mt][nf][r] + b));
    }
  }
  __syncthreads();

  // -------- phase 2: q,k,v = sX @ W*^T + b*
  const float* Wm[3] = {Wq, Wk, Wv};
  const float* bm[3] = {bq, bk, bv};
#pragma unroll
  for (int mat = 0; mat < 3; ++mat) {
    f32x4 acc[2][4];
#pragma unroll
    for (int a = 0; a < 2; ++a)
#pragma unroll
      for (int b = 0; b < 4; ++b) acc[a][b] = (f32x4){0.f,0.f,0.f,0.f};
    for (int ks = 0; ks < 8; ++ks) {
      { const float* wr = Wm[mat] + (size_t)tid * 256 + ks * 32;
        short8 w0 = cvt8(wr), w1 = cvt8(wr+8), w2 = cvt8(wr+16), w3 = cvt8(wr+24);
        ushort_t* d = &sW[tid * 40];
        *(short8*)d = w0; *(short8*)(d+8) = w1; *(short8*)(d+16) = w2; *(short8*)(d+24) = w3; }
      __syncthreads();
      short8 af[2];
#pragma unroll
      for (int mt = 0; mt < 2; ++mt)
        af[mt] = *(const short8*)&sX[(mt * 16 + li) * 288 + ks * 32 + g * 8];
#pragma unroll
      for (int nf = 0; nf < 4; ++nf) {
        short8 bf = *(const short8*)&sW[(w * 64 + nf * 16 + li) * 40 + g * 8];
#pragma unroll
        for (int mt = 0; mt < 2; ++mt) acc[mt][nf] = MFMA_BF16(af[mt], bf, acc[mt][nf]);
      }
      __syncthreads();
    }
#pragma unroll
    for (int nf = 0; nf < 4; ++nf) {
      int col = w * 64 + nf * 16 + li;
      float b = bm[mat][col];
#pragma unroll
      for (int mt = 0; mt < 2; ++mt)
#pragma unroll
        for (int r = 0; r < 4; ++r) {
          float vv = acc[mt][nf][r] + b;
          int row = mt * 16 + g * 4 + r;
          if (mat == 0)      sQ[row * 264 + col] = f2bf(vv * 0.125f);   // 1/sqrt(64)
          else if (mat == 1) sK[row * 264 + col] = f2bf(vv);
          else               sVT[col * 36 + row] = f2bf(vv);
        }
    }
  }
  __syncthreads();

  // -------- phase 3: per-head attention (head = wave)
  {
    f32x4 sc[2][2];
#pragma unroll
    for (int a = 0; a < 2; ++a)
#pragma unroll
      for (int b = 0; b < 2; ++b) sc[a][b] = (f32x4){0.f,0.f,0.f,0.f};
    for (int ks = 0; ks < 2; ++ks) {
      short8 af[2], bf[2];
#pragma unroll
      for (int t = 0; t < 2; ++t) {
        af[t] = *(const short8*)&sQ[(t * 16 + li) * 264 + w * 64 + ks * 32 + g * 8];
        bf[t] = *(const short8*)&sK[(t * 16 + li) * 264 + w * 64 + ks * 32 + g * 8];
      }
#pragma unroll
      for (int mt = 0; mt < 2; ++mt)
#pragma unroll
        for (int nt = 0; nt < 2; ++nt)
          sc[mt][nt] = MFMA_BF16(af[mt], bf[nt], sc[mt][nt]);
    }
    // mask + row softmax (row = mt*16+g*4+r, key = nt*16+li); q pre-scaled
#pragma unroll
    for (int mt = 0; mt < 2; ++mt) {
#pragma unroll
      for (int nt = 0; nt < 2; ++nt) {
        bool ok = (nt * 16 + li) < dg;
#pragma unroll
        for (int r = 0; r < 4; ++r) sc[mt][nt][r] = ok ? sc[mt][nt][r] : -1e30f;
      }
#pragma unroll
      for (int r = 0; r < 4; ++r) {
        float mx = fmaxf(sc[mt][0][r], sc[mt][1][r]);
#pragma unroll
        for (int d = 1; d < 16; d <<= 1) mx = fmaxf(mx, __shfl_xor(mx, d));
        float s0 = expf(sc[mt][0][r] - mx);
        float s1 = expf(sc[mt][1][r] - mx);
        float sum = s0 + s1;
#pragma unroll
        for (int d = 1; d < 16; d <<= 1) sum += __shfl_xor(sum, d);
        float inv = 1.0f / sum;
        sc[mt][0][r] = s0 * inv;
        sc[mt][1][r] = s1 * inv;
      }
    }
    __syncthreads();           // all sQ/sK reads done -> safe to overlay P, O

    float* P = (float*)sX + w * (32 * 36);
#pragma unroll
    for (int mt = 0; mt < 2; ++mt)
#pragma unroll
      for (int nt = 0; nt < 2; ++nt)
#pragma unroll
        for (int r = 0; r < 4; ++r)
          P[(mt * 16 + g * 4 + r) * 36 + nt * 16 + li] = sc[mt][nt][r];

    short8 pa[2];
#pragma unroll
    for (int mt = 0; mt < 2; ++mt) {
      f32x4 p0 = *(const f32x4*)&P[(mt * 16 + li) * 36 + g * 8];
      f32x4 p1 = *(const f32x4*)&P[(mt * 16 + li) * 36 + g * 8 + 4];
      short8 t;
#pragma unroll
      for (int j = 0; j < 4; ++j) { t[j] = (short)f2bf(p0[j]); t[4 + j] = (short)f2bf(p1[j]); }
      pa[mt] = t;
    }
    f32x4 o[2][4];
#pragma unroll
    for (int a = 0; a < 2; ++a)
#pragma unroll
      for (int b = 0; b < 4; ++b) o[a][b] = (f32x4){0.f,0.f,0.f,0.f};
#pragma unroll
    for (int nf = 0; nf < 4; ++nf) {
      int col = w * 64 + nf * 16 + li;
      short4_t l4 = *(const short4_t*)&sVT[col * 36 + g * 8];
      short4_t h4 = *(const short4_t*)&sVT[col * 36 + g * 8 + 4];
      short8 bfr;
#pragma unroll
      for (int j = 0; j < 4; ++j) { bfr[j] = l4[j]; bfr[4 + j] = h4[j]; }
#pragma unroll
      for (int mt = 0; mt < 2; ++mt) o[mt][nf] = MFMA_BF16(pa[mt], bfr, o[mt][nf]);
    }
    ushort_t* sO = sQ;
#pragma unroll
    for (int mt = 0; mt < 2; ++mt)
#pragma unroll
      for (int nf = 0; nf < 4; ++nf)
#pragma unroll
        for (int r = 0; r < 4; ++r)
          sO[(mt * 16 + g * 4 + r) * 264 + w * 64 + nf * 16 + li] = f2bf(o[mt][nf][r]);
  }
  __syncthreads();

  // -------- phase 4: Wo GEMM + gelu + group softmax + scatter
  {
    const ushort_t* sO = sQ;
    f32x4 acc[2][4];
#pragma unroll
    for (int a = 0; a < 2; ++a)
#pragma unroll
      for (int b = 0; b < 4; ++b) acc[a][b] = (f32x4){0.f,0.f,0.f,0.f};
    for (int ks = 0; ks < 8; ++ks) {
      { const float* wr = Wo + (size_t)tid * 256 + ks * 32;
        short8 w0 = cvt8(wr), w1 = cvt8(wr+8), w2 = cvt8(wr+16), w3 = cvt8(wr+24);
        ushort_t* d = &sW[tid * 40];
        *(short8*)d = w0; *(short8*)(d+8) = w1; *(short8*)(d+16) = w2; *(short8*)(d+24) = w3; }
      __syncthreads();
      short8 af[2];
#pragma unroll
      for (int mt = 0; mt < 2; ++mt)
        af[mt] = *(const short8*)&sO[(mt * 16 + li) * 264 + ks * 32 + g * 8];
#pragma unroll
      for (int nf = 0; nf < 4; ++nf) {
        short8 bf = *(const short8*)&sW[(w * 64 + nf * 16 + li) * 40 + g * 8];
#pragma unroll
        for (int mt = 0; mt < 2; ++mt) acc[mt][nf] = MFMA_BF16(af[mt], bf, acc[mt][nf]);
      }
      __syncthreads();
    }
    float hg[2][4][4];
#pragma unroll
    for (int nf = 0; nf < 4; ++nf) {
      float b = bo[w * 64 + nf * 16 + li];
#pragma unroll
      for (int mt = 0; mt < 2; ++mt)
#pragma unroll
        for (int r = 0; r < 4; ++r) hg[mt][nf][r] = gelu_f(acc[mt][nf][r] + b);
    }
    // logits (head = w): gate = frags 2,3 ; sum over the 32 gate cols (reduce over li)
    float lp[2][4];
#pragma unroll
    for (int mt = 0; mt < 2; ++mt)
#pragma unroll
      for (int r = 0; r < 4; ++r) lp[mt][r] = hg[mt][2][r] + hg[mt][3][r];
#pragma unroll
    for (int d = 1; d < 16; d <<= 1)
#pragma unroll
      for (int mt = 0; mt < 2; ++mt)
#pragma unroll
        for (int r = 0; r < 4; ++r) lp[mt][r] += __shfl_xor(lp[mt][r], d);
    // group softmax over rows (each lane holds rows {mt*16+g*4+r}; reduce over g)
    float ml[2][4], mx = -1e30f;
#pragma unroll
    for (int mt = 0; mt < 2; ++mt)
#pragma unroll
      for (int r = 0; r < 4; ++r) {
        int row = mt * 16 + g * 4 + r;
        ml[mt][r] = (row < dg) ? lp[mt][r] * (1.f / 32.f) : -1e30f;
        mx = fmaxf(mx, ml[mt][r]);
      }
    mx = fmaxf(mx, __shfl_xor(mx, 16));
    mx = fmaxf(mx, __shfl_xor(mx, 32));
    float ee[2][4], ss = 0.f;
#pragma unroll
    for (int mt = 0; mt < 2; ++mt)
#pragma unroll
      for (int r = 0; r < 4; ++r) {
        int row = mt * 16 + g * 4 + r;
        ee[mt][r] = (row < dg) ? expf(ml[mt][r] - mx) : 0.f;
        ss += ee[mt][r];
      }
    ss += __shfl_xor(ss, 16);
    ss += __shfl_xor(ss, 32);
    float inv = 1.0f / ss;
#pragma unroll
    for (int mt = 0; mt < 2; ++mt)
#pragma unroll
      for (int r = 0; r < 4; ++r) {
        int row = mt * 16 + g * 4 + r;
        if (row < dg) {
          int eo = e1[st + row];
          float a = ee[mt][r] * inv;
#pragma unroll
          for (int nf = 0; nf < 2; ++nf)
            atomicAdd(&dout[(size_t)eo * 128 + w * 32 + nf * 16 + li], hg[mt][nf][r] * a);
        }
      }
  }
}

// ---------------------------------------------------------------- launch
extern "C" void kernel_launch(void* const* d_in, const int* in_sizes, int n_in,
                              void* d_out, int out_size, void* d_ws, size_t ws_size,
                              hipStream_t stream) {
  (void)n_in; (void)ws_size;
  const float* x  = (const float*)d_in[0];
  const float* Wc = (const float*)d_in[1];
  const float* bc = (const float*)d_in[2];
  const float* Wq = (const float*)d_in[3];
  const float* bq = (const float*)d_in[4];
  const float* Wk = (const float*)d_in[5];
  const float* bk = (const float*)d_in[6];
  const float* Wv = (const float*)d_in[7];
  const float* bv = (const float*)d_in[8];
  const float* Wo = (const float*)d_in[9];
  const float* bo = (const float*)d_in[10];
  const int* e0  = (const int*)d_in[11];
  const int* e1  = (const int*)d_in[12];
  const int* pos = (const int*)d_in[13];
  const int m = in_sizes[11];
  const int n = in_sizes[0] / 128;

  int* startp = (int*)d_ws;
  int* degp = startp + n;

  // d_out is poisoned before every timed call -> zero it ourselves (f32 accumulator)
  hipMemsetAsync(d_out, 0, (size_t)out_size * sizeof(float), stream);
  hipMemsetAsync(startp, 0, (size_t)n * 2 * sizeof(int), stream);

  k_prep<<<(m + 255) / 256, 256, 0, stream>>>(e0, pos, m, startp, degp);
  k_fused<<<n, 256, 0, stream>>>(x, Wc, bc, Wq, bq, Wk, bk, Wv, bv, Wo, bo,
                                 e1, startp, degp, (float*)d_out, m);
}

// Round 5
// 915.959 us; speedup vs baseline: 2.5173x; 2.5173x over previous
//
#include <hip/hip_runtime.h>
#include <math.h>

typedef unsigned short ushort_t;
typedef __attribute__((ext_vector_type(8))) short short8;
typedef __attribute__((ext_vector_type(4))) short short4_t;
typedef __attribute__((ext_vector_type(4))) float f32x4;

#define MFMA_BF16(a,b,c) __builtin_amdgcn_mfma_f32_16x16x32_bf16((a),(b),(c),0,0,0)

__device__ __forceinline__ ushort_t f2bf(float f){
  union { float f; unsigned int i; } v; v.f = f;
  unsigned int r = v.i + 0x7fffu + ((v.i >> 16) & 1u);
  return (ushort_t)(r >> 16);
}
__device__ __forceinline__ float gelu_f(float x){
  return 0.5f * x * (1.0f + erff(x * 0.70710678118654752f));
}
// load 8 consecutive f32 -> 8 bf16
__device__ __forceinline__ short8 cvt8(const float* __restrict__ p){
  f32x4 a = *(const f32x4*)p;
  f32x4 b = *(const f32x4*)(p + 4);
  short8 t;
#pragma unroll
  for (int j = 0; j < 4; ++j) { t[j] = (short)f2bf(a[j]); t[4 + j] = (short)f2bf(b[j]); }
  return t;
}
__device__ __forceinline__ short8 pack2(short4_t lo, short4_t hi){
  short8 t;
#pragma unroll
  for (int j = 0; j < 4; ++j) { t[j] = lo[j]; t[4 + j] = hi[j]; }
  return t;
}

// ---------------------------------------------------------------- prep: CSR
__global__ void k_prep(const int* __restrict__ e0, const int* __restrict__ pos,
                       int m, int* __restrict__ startp, int* __restrict__ degp){
  int i = blockIdx.x * 256 + threadIdx.x;
  if (i >= m) return;
  int s = e0[i];
  if (pos[i] == 0) startp[s] = i;
  if (i == m - 1 || e0[i + 1] != s) degp[s] = pos[i] + 1;
}

// ---------------------------------------------------------------- weights f32 -> bf16 (once)
__global__ void k_wcvt(const float* __restrict__ Wc, const float* __restrict__ Wq,
                       const float* __restrict__ Wk, const float* __restrict__ Wv,
                       const float* __restrict__ Wo, ushort_t* __restrict__ wb){
  int i = blockIdx.x * 256 + threadIdx.x;
  if (i >= 5 * 65536) return;
  int s = i >> 16, off = i & 65535;
  const float* src = (s == 0) ? Wc : (s == 1) ? Wq : (s == 2) ? Wk : (s == 3) ? Wv : Wo;
  wb[i] = f2bf(src[off]);
}

// ================================================================ FUSED (2 nodes / block)
// Weights consumed per-wave straight from global (bf16 if WB, else f32+cvt):
// wave w only touches output cols [w*64, w*64+64) -> its B-fragments are private.
// No LDS weight staging; only 3 barriers per block.
template<bool WB>
__global__ __launch_bounds__(256, 1) void k_fused2(
    const float* __restrict__ x,
    const ushort_t* __restrict__ wb,     // [5][256*256] bf16 (WB) or unused
    const float* __restrict__ Wcf, const float* __restrict__ bc,
    const float* __restrict__ Wqf, const float* __restrict__ bq,
    const float* __restrict__ Wkf, const float* __restrict__ bk,
    const float* __restrict__ Wvf, const float* __restrict__ bv,
    const float* __restrict__ Wof, const float* __restrict__ bo,
    const int* __restrict__ e1,
    const int* __restrict__ startp, const int* __restrict__ degp,
    float* __restrict__ dout, int m, int n)
{
  __shared__ __align__(16) ushort_t sX[64 * 264];        // ex tile; per-wave P overlays later
  __shared__ __align__(16) ushort_t sQ[64 * 264];        // q tile; attn-out overlays (same cols per wave)
  __shared__ __align__(16) ushort_t sK[64 * 264];        // k tile
  __shared__ __align__(16) ushort_t sVT[2 * 256 * 40];   // per-node V^T [col][40 pad key]

  const int tid = threadIdx.x;
  const int w = tid >> 6, lane = tid & 63;
  const int g = lane >> 4, li = lane & 15;

  int st2[2], dg2[2], nodev[2];
#pragma unroll
  for (int nd = 0; nd < 2; ++nd) {
    int node = blockIdx.x * 2 + nd;
    nodev[nd] = min(node, n - 1);
    if (node < n) { st2[nd] = startp[node]; dg2[nd] = degp[node]; }
    else { st2[nd] = 0; dg2[nd] = 0; }
  }
  if (dg2[0] <= 0 && dg2[1] <= 0) return;

  // A-row edge ids (A-fragment row = mt*16 + li)
  int dstn[4];
#pragma unroll
  for (int mt = 0; mt < 4; ++mt) {
    int nd = mt >> 1;
    int rin = (mt & 1) * 16 + li;
    int d = dg2[nd];
    int e = (d > 0) ? (st2[nd] + min(rin, d - 1)) : 0;
    dstn[mt] = e1[e];
  }

  const int colbase = w * 64;

  // -------- phase 1: ex = gelu([x_src | x_dst] Wc^T + bc) -> sX
  {
    f32x4 acc[4][4];
#pragma unroll
    for (int a = 0; a < 4; ++a)
#pragma unroll
      for (int b = 0; b < 4; ++b) acc[a][b] = (f32x4){0.f,0.f,0.f,0.f};
#pragma unroll
    for (int ks = 0; ks < 8; ++ks) {
      short8 bf[4];
#pragma unroll
      for (int nf = 0; nf < 4; ++nf) {
        int off = (colbase + nf * 16 + li) * 256 + ks * 32 + g * 8;
        bf[nf] = WB ? *(const short8*)(wb + off) : cvt8(Wcf + off);
      }
      int k0 = ks * 32 + g * 8;
      short8 af[4];
#pragma unroll
      for (int mt = 0; mt < 4; ++mt) {
        const float* src = (k0 < 128) ? (x + (size_t)nodev[mt >> 1] * 128 + k0)
                                      : (x + (size_t)dstn[mt] * 128 + (k0 - 128));
        af[mt] = cvt8(src);
      }
#pragma unroll
      for (int nf = 0; nf < 4; ++nf)
#pragma unroll
        for (int mt = 0; mt < 4; ++mt)
          acc[mt][nf] = MFMA_BF16(af[mt], bf[nf], acc[mt][nf]);
    }
#pragma unroll
    for (int nf = 0; nf < 4; ++nf) {
      int col = colbase + nf * 16 + li;
      float b = bc[col];
#pragma unroll
      for (int mt = 0; mt < 4; ++mt)
#pragma unroll
        for (int r = 0; r < 4; ++r)
          sX[(mt * 16 + g * 4 + r) * 264 + col] = f2bf(gelu_f(acc[mt][nf][r] + b));
    }
  }
  __syncthreads();   // barrier 1: sX complete (phase 2 reads all cols)

  // -------- phase 2: q,k,v = sX @ W*^T + b*
#pragma unroll
  for (int mat = 0; mat < 3; ++mat) {
    const ushort_t* wp = wb + (size_t)(1 + mat) * 65536;
    const float* wf = (mat == 0) ? Wqf : (mat == 1) ? Wkf : Wvf;
    const float* bb = (mat == 0) ? bq : (mat == 1) ? bk : bv;
    f32x4 acc[4][4];
#pragma unroll
    for (int a = 0; a < 4; ++a)
#pragma unroll
      for (int b = 0; b < 4; ++b) acc[a][b] = (f32x4){0.f,0.f,0.f,0.f};
#pragma unroll
    for (int ks = 0; ks < 8; ++ks) {
      short8 bf[4];
#pragma unroll
      for (int nf = 0; nf < 4; ++nf) {
        int off = (colbase + nf * 16 + li) * 256 + ks * 32 + g * 8;
        bf[nf] = WB ? *(const short8*)(wp + off) : cvt8(wf + off);
      }
      short8 af[4];
#pragma unroll
      for (int mt = 0; mt < 4; ++mt)
        af[mt] = *(const short8*)&sX[(mt * 16 + li) * 264 + ks * 32 + g * 8];
#pragma unroll
      for (int nf = 0; nf < 4; ++nf)
#pragma unroll
        for (int mt = 0; mt < 4; ++mt)
          acc[mt][nf] = MFMA_BF16(af[mt], bf[nf], acc[mt][nf]);
    }
#pragma unroll
    for (int nf = 0; nf < 4; ++nf) {
      int col = colbase + nf * 16 + li;
      float b = bb[col];
#pragma unroll
      for (int mt = 0; mt < 4; ++mt)
#pragma unroll
        for (int r = 0; r < 4; ++r) {
          float vv = acc[mt][nf][r] + b;
          int row = mt * 16 + g * 4 + r;
          if (mat == 0)      sQ[row * 264 + col] = f2bf(vv * 0.125f);  // 1/sqrt(64)
          else if (mat == 1) sK[row * 264 + col] = f2bf(vv);
          else {
            int nd = mt >> 1, rin = (mt & 1) * 16 + g * 4 + r;
            sVT[((size_t)nd * 256 + col) * 40 + rin] = f2bf(vv);
          }
        }
    }
  }
  __syncthreads();   // barrier 2: before P overlays sX (other waves' sX reads done)

  // -------- phase 3: per-head attention (head = wave), loop over the 2 nodes
  {
    ushort_t* Pb = sX + w * (32 * 40);   // per-wave P tile [32][40] bf16 (private)
#pragma unroll
    for (int nd = 0; nd < 2; ++nd) {
      const int rb = nd * 32;
      const int dgn = dg2[nd];
      f32x4 sc[2][2];
#pragma unroll
      for (int a = 0; a < 2; ++a)
#pragma unroll
        for (int b = 0; b < 2; ++b) sc[a][b] = (f32x4){0.f,0.f,0.f,0.f};
#pragma unroll
      for (int ks = 0; ks < 2; ++ks) {
        short8 afq[2], bfk[2];
#pragma unroll
        for (int t = 0; t < 2; ++t) {
          afq[t] = *(const short8*)&sQ[(rb + t * 16 + li) * 264 + colbase + ks * 32 + g * 8];
          bfk[t] = *(const short8*)&sK[(rb + t * 16 + li) * 264 + colbase + ks * 32 + g * 8];
        }
#pragma unroll
        for (int mt = 0; mt < 2; ++mt)
#pragma unroll
          for (int nt = 0; nt < 2; ++nt)
            sc[mt][nt] = MFMA_BF16(afq[mt], bfk[nt], sc[mt][nt]);
      }
      // mask + per-row softmax (row = mt*16+g*4+r, key = nt*16+li)
#pragma unroll
      for (int mt = 0; mt < 2; ++mt) {
#pragma unroll
        for (int nt = 0; nt < 2; ++nt) {
          bool ok = (nt * 16 + li) < dgn;
#pragma unroll
          for (int r = 0; r < 4; ++r) sc[mt][nt][r] = ok ? sc[mt][nt][r] : -1e30f;
        }
#pragma unroll
        for (int r = 0; r < 4; ++r) {
          float mx = fmaxf(sc[mt][0][r], sc[mt][1][r]);
#pragma unroll
          for (int d = 1; d < 16; d <<= 1) mx = fmaxf(mx, __shfl_xor(mx, d));
          float s0 = expf(sc[mt][0][r] - mx);
          float s1 = expf(sc[mt][1][r] - mx);
          float sum = s0 + s1;
#pragma unroll
          for (int d = 1; d < 16; d <<= 1) sum += __shfl_xor(sum, d);
          float inv = 1.0f / sum;
          sc[mt][0][r] = s0 * inv;
          sc[mt][1][r] = s1 * inv;
        }
      }
      // P -> LDS as bf16 (A-operand transpose)
#pragma unroll
      for (int mt = 0; mt < 2; ++mt)
#pragma unroll
        for (int nt = 0; nt < 2; ++nt)
#pragma unroll
          for (int r = 0; r < 4; ++r)
            Pb[(mt * 16 + g * 4 + r) * 40 + nt * 16 + li] = f2bf(sc[mt][nt][r]);
      short8 pa[2];
#pragma unroll
      for (int mt = 0; mt < 2; ++mt) {
        const ushort_t* pr = &Pb[(mt * 16 + li) * 40 + g * 8];
        pa[mt] = pack2(*(const short4_t*)pr, *(const short4_t*)(pr + 4));
      }
      // PV
      f32x4 o[2][4];
#pragma unroll
      for (int a = 0; a < 2; ++a)
#pragma unroll
        for (int b = 0; b < 4; ++b) o[a][b] = (f32x4){0.f,0.f,0.f,0.f};
#pragma unroll
      for (int nf = 0; nf < 4; ++nf) {
        const ushort_t* vp = &sVT[((size_t)nd * 256 + colbase + nf * 16 + li) * 40 + g * 8];
        short8 bfr = pack2(*(const short4_t*)vp, *(const short4_t*)(vp + 4));
#pragma unroll
        for (int mt = 0; mt < 2; ++mt) o[mt][nf] = MFMA_BF16(pa[mt], bfr, o[mt][nf]);
      }
      // attn-out overlays sQ: wave w writes only its own cols [w*64, w*64+64)
#pragma unroll
      for (int mt = 0; mt < 2; ++mt)
#pragma unroll
        for (int nf = 0; nf < 4; ++nf)
#pragma unroll
          for (int r = 0; r < 4; ++r)
            sQ[(rb + mt * 16 + g * 4 + r) * 264 + colbase + nf * 16 + li] = f2bf(o[mt][nf][r]);
    }
  }
  __syncthreads();   // barrier 3: attn-out complete (phase 4 reads all cols)

  // -------- phase 4: Wo GEMM + gelu + per-node softmax over logits + scatter
  {
    const ushort_t* wp = wb + (size_t)4 * 65536;
    f32x4 acc[4][4];
#pragma unroll
    for (int a = 0; a < 4; ++a)
#pragma unroll
      for (int b = 0; b < 4; ++b) acc[a][b] = (f32x4){0.f,0.f,0.f,0.f};
#pragma unroll
    for (int ks = 0; ks < 8; ++ks) {
      short8 bf[4];
#pragma unroll
      for (int nf = 0; nf < 4; ++nf) {
        int off = (colbase + nf * 16 + li) * 256 + ks * 32 + g * 8;
        bf[nf] = WB ? *(const short8*)(wp + off) : cvt8(Wof + off);
      }
      short8 af[4];
#pragma unroll
      for (int mt = 0; mt < 4; ++mt)
        af[mt] = *(const short8*)&sQ[(mt * 16 + li) * 264 + ks * 32 + g * 8];
#pragma unroll
      for (int nf = 0; nf < 4; ++nf)
#pragma unroll
        for (int mt = 0; mt < 4; ++mt)
          acc[mt][nf] = MFMA_BF16(af[mt], bf[nf], acc[mt][nf]);
    }
    // gelu in place
#pragma unroll
    for (int nf = 0; nf < 4; ++nf) {
      float b = bo[colbase + nf * 16 + li];
#pragma unroll
      for (int mt = 0; mt < 4; ++mt)
#pragma unroll
        for (int r = 0; r < 4; ++r) acc[mt][nf][r] = gelu_f(acc[mt][nf][r] + b);
    }
    // logits for head w: mean of gate cols (nf 2,3), reduce over li
    float lp[4][4];
#pragma unroll
    for (int mt = 0; mt < 4; ++mt)
#pragma unroll
      for (int r = 0; r < 4; ++r) lp[mt][r] = acc[mt][2][r] + acc[mt][3][r];
#pragma unroll
    for (int d = 1; d < 16; d <<= 1)
#pragma unroll
      for (int mt = 0; mt < 4; ++mt)
#pragma unroll
        for (int r = 0; r < 4; ++r) lp[mt][r] += __shfl_xor(lp[mt][r], d);
    // per-node group softmax + scatter
#pragma unroll
    for (int nd = 0; nd < 2; ++nd) {
      const int dgn = dg2[nd], stn = st2[nd];
      float ml[2][4], mx = -1e30f;
#pragma unroll
      for (int mt2 = 0; mt2 < 2; ++mt2)
#pragma unroll
        for (int r = 0; r < 4; ++r) {
          int rin = mt2 * 16 + g * 4 + r;
          ml[mt2][r] = (rin < dgn) ? lp[nd * 2 + mt2][r] * (1.f / 32.f) : -1e30f;
          mx = fmaxf(mx, ml[mt2][r]);
        }
      mx = fmaxf(mx, __shfl_xor(mx, 16));
      mx = fmaxf(mx, __shfl_xor(mx, 32));
      float ee[2][4], ss = 0.f;
#pragma unroll
      for (int mt2 = 0; mt2 < 2; ++mt2)
#pragma unroll
        for (int r = 0; r < 4; ++r) {
          int rin = mt2 * 16 + g * 4 + r;
          ee[mt2][r] = (rin < dgn) ? expf(ml[mt2][r] - mx) : 0.f;
          ss += ee[mt2][r];
        }
      ss += __shfl_xor(ss, 16);
      ss += __shfl_xor(ss, 32);
      float inv = 1.0f / ss;
#pragma unroll
      for (int mt2 = 0; mt2 < 2; ++mt2)
#pragma unroll
        for (int r = 0; r < 4; ++r) {
          int rin = mt2 * 16 + g * 4 + r;
          if (rin < dgn) {
            int eo = e1[stn + rin];
            float a = ee[mt2][r] * inv;
            atomicAdd(&dout[(size_t)eo * 128 + w * 32 + li],      acc[nd * 2 + mt2][0][r] * a);
            atomicAdd(&dout[(size_t)eo * 128 + w * 32 + 16 + li], acc[nd * 2 + mt2][1][r] * a);
          }
        }
    }
  }
}

// ---------------------------------------------------------------- launch
extern "C" void kernel_launch(void* const* d_in, const int* in_sizes, int n_in,
                              void* d_out, int out_size, void* d_ws, size_t ws_size,
                              hipStream_t stream) {
  (void)n_in;
  const float* x  = (const float*)d_in[0];
  const float* Wc = (const float*)d_in[1];
  const float* bc = (const float*)d_in[2];
  const float* Wq = (const float*)d_in[3];
  const float* bq = (const float*)d_in[4];
  const float* Wk = (const float*)d_in[5];
  const float* bk = (const float*)d_in[6];
  const float* Wv = (const float*)d_in[7];
  const float* bv = (const float*)d_in[8];
  const float* Wo = (const float*)d_in[9];
  const float* bo = (const float*)d_in[10];
  const int* e0  = (const int*)d_in[11];
  const int* e1  = (const int*)d_in[12];
  const int* pos = (const int*)d_in[13];
  const int m = in_sizes[11];
  const int n = in_sizes[0] / 128;

  const size_t WBYTES = (size_t)5 * 65536 * sizeof(ushort_t);   // 640 KB
  const bool use_wb = ws_size >= WBYTES + (size_t)n * 2 * sizeof(int);

  ushort_t* wb = (ushort_t*)d_ws;
  int* startp = use_wb ? (int*)((char*)d_ws + WBYTES) : (int*)d_ws;
  int* degp = startp + n;

  hipMemsetAsync(d_out, 0, (size_t)out_size * sizeof(float), stream);
  hipMemsetAsync(startp, 0, (size_t)n * 2 * sizeof(int), stream);

  k_prep<<<(m + 255) / 256, 256, 0, stream>>>(e0, pos, m, startp, degp);
  const int nb = (n + 1) / 2;
  if (use_wb) {
    k_wcvt<<<(5 * 65536 + 255) / 256, 256, 0, stream>>>(Wc, Wq, Wk, Wv, Wo, wb);
    k_fused2<true><<<nb, 256, 0, stream>>>(x, wb, Wc, bc, Wq, bq, Wk, bk, Wv, bv, Wo, bo,
                                           e1, startp, degp, (float*)d_out, m, n);
  } else {
    k_fused2<false><<<nb, 256, 0, stream>>>(x, nullptr, Wc, bc, Wq, bq, Wk, bk, Wv, bv, Wo, bo,
                                            e1, startp, degp, (float*)d_out, m, n);
  }
}

// Round 6
// 760.414 us; speedup vs baseline: 3.0323x; 1.2046x over previous
//
#include <hip/hip_runtime.h>
#include <math.h>

typedef unsigned short ushort_t;
typedef __attribute__((ext_vector_type(8))) short short8;
typedef __attribute__((ext_vector_type(4))) short short4_t;
typedef __attribute__((ext_vector_type(4))) float f32x4;

#define MFMA_BF16(a,b,c) __builtin_amdgcn_mfma_f32_16x16x32_bf16((a),(b),(c),0,0,0)

__device__ __forceinline__ ushort_t f2bf(float f){
  union { float f; unsigned int i; } v; v.f = f;
  unsigned int r = v.i + 0x7fffu + ((v.i >> 16) & 1u);
  return (ushort_t)(r >> 16);
}
__device__ __forceinline__ float gelu_f(float x){
  return 0.5f * x * (1.0f + erff(x * 0.70710678118654752f));
}
// load 8 consecutive f32 -> 8 bf16
__device__ __forceinline__ short8 cvt8(const float* __restrict__ p){
  f32x4 a = *(const f32x4*)p;
  f32x4 b = *(const f32x4*)(p + 4);
  short8 t;
#pragma unroll
  for (int j = 0; j < 4; ++j) { t[j] = (short)f2bf(a[j]); t[4 + j] = (short)f2bf(b[j]); }
  return t;
}
__device__ __forceinline__ short8 pack2(short4_t lo, short4_t hi){
  short8 t;
#pragma unroll
  for (int j = 0; j < 4; ++j) { t[j] = lo[j]; t[4 + j] = hi[j]; }
  return t;
}

// ---------------------------------------------------------------- prep: CSR
__global__ void k_prep(const int* __restrict__ e0, const int* __restrict__ pos,
                       int m, int* __restrict__ startp, int* __restrict__ degp){
  int i = blockIdx.x * 256 + threadIdx.x;
  if (i >= m) return;
  int s = e0[i];
  if (pos[i] == 0) startp[s] = i;
  if (i == m - 1 || e0[i + 1] != s) degp[s] = pos[i] + 1;
}

// ---------------------------------------------------------------- weights f32 -> bf16 (once)
__global__ void k_wcvt(const float* __restrict__ Wc, const float* __restrict__ Wq,
                       const float* __restrict__ Wk, const float* __restrict__ Wv,
                       const float* __restrict__ Wo, ushort_t* __restrict__ wb){
  int i = blockIdx.x * 256 + threadIdx.x;
  if (i >= 5 * 65536) return;
  int s = i >> 16, off = i & 65535;
  const float* src = (s == 0) ? Wc : (s == 1) ? Wq : (s == 2) ? Wk : (s == 3) ? Wv : Wo;
  wb[i] = f2bf(src[off]);
}

// ================================================================ FUSED (1 node/block, 2 blocks/CU)
// 80.4 KB LDS -> two independent 256-thread blocks per CU (2 waves/SIMD TLP).
// Weights read per-wave straight from global bf16 (wave w owns cols [w*64,w*64+64)).
template<bool WB>
__global__ __launch_bounds__(256, 2) void k_fused3(
    const float* __restrict__ x,
    const ushort_t* __restrict__ wb,     // [5][256*256] bf16 (WB) or unused
    const float* __restrict__ Wcf, const float* __restrict__ bc,
    const float* __restrict__ Wqf, const float* __restrict__ bq,
    const float* __restrict__ Wkf, const float* __restrict__ bk,
    const float* __restrict__ Wvf, const float* __restrict__ bv,
    const float* __restrict__ Wof, const float* __restrict__ bo,
    const int* __restrict__ e1,
    const int* __restrict__ startp, const int* __restrict__ degp,
    float* __restrict__ dout, int m, int n)
{
  __shared__ __align__(16) ushort_t sX[32 * 264];   // ex tile; attn-out overlays in phase 3
  __shared__ __align__(16) ushort_t sQ[32 * 264];   // q tile
  __shared__ __align__(16) ushort_t sK[32 * 264];   // k tile
  __shared__ __align__(16) ushort_t sVT[256 * 40];  // v^T [col][40 pad key]
  __shared__ __align__(16) ushort_t sPX[4608];      // union: {x-stage: [32][136] dst + [128] src} / {4 x P[32][36]}

  const int node = blockIdx.x;
  const int st = startp[node], dg = degp[node];
  if (dg <= 0) return;
  const int tid = threadIdx.x;
  const int w = tid >> 6, lane = tid & 63;
  const int g = lane >> 4, li = lane & 15;
  const int colbase = w * 64;

  // -------- phase 0: stage A rows into LDS (bf16): dst rows [32][136], src row [128]
  {
    int r = tid >> 3, seg = tid & 7;                 // r 0..31, seg 0..7 (16 f32 each)
    int dn = e1[st + min(r, dg - 1)];
    const float* s = x + (size_t)dn * 128 + seg * 16;
    *(short8*)&sPX[r * 136 + seg * 16]     = cvt8(s);
    *(short8*)&sPX[r * 136 + seg * 16 + 8] = cvt8(s + 8);
    if (tid < 16)
      *(short8*)&sPX[4352 + tid * 8] = cvt8(x + (size_t)node * 128 + tid * 8);
  }
  __syncthreads();

  // -------- phase 1: ex = gelu([x_src | x_dst] Wc^T + bc) -> sX
  {
    f32x4 acc[2][4];
#pragma unroll
    for (int a = 0; a < 2; ++a)
#pragma unroll
      for (int b = 0; b < 4; ++b) acc[a][b] = (f32x4){0.f,0.f,0.f,0.f};
#pragma unroll
    for (int ks = 0; ks < 8; ++ks) {
      short8 bf[4];
#pragma unroll
      for (int nf = 0; nf < 4; ++nf) {
        int off = (colbase + nf * 16 + li) * 256 + ks * 32 + g * 8;
        bf[nf] = WB ? *(const short8*)(wb + off) : cvt8(Wcf + off);
      }
      short8 af[2];
      if (ks < 4) {                                   // k0 = ks*32+g*8 < 128: src-x half (row-uniform)
        short8 t = *(const short8*)&sPX[4352 + ks * 32 + g * 8];
        af[0] = t; af[1] = t;
      } else {                                        // dst-x half
#pragma unroll
        for (int mt = 0; mt < 2; ++mt)
          af[mt] = *(const short8*)&sPX[(mt * 16 + li) * 136 + (ks - 4) * 32 + g * 8];
      }
#pragma unroll
      for (int nf = 0; nf < 4; ++nf)
#pragma unroll
        for (int mt = 0; mt < 2; ++mt)
          acc[mt][nf] = MFMA_BF16(af[mt], bf[nf], acc[mt][nf]);
    }
#pragma unroll
    for (int nf = 0; nf < 4; ++nf) {
      int col = colbase + nf * 16 + li;
      float b = bc[col];
#pragma unroll
      for (int mt = 0; mt < 2; ++mt)
#pragma unroll
        for (int r = 0; r < 4; ++r)
          sX[(mt * 16 + g * 4 + r) * 264 + col] = f2bf(gelu_f(acc[mt][nf][r] + b));
    }
  }
  __syncthreads();   // barrier: sX complete

  // -------- phase 2: q,k,v = sX @ W*^T + b*
#pragma unroll
  for (int mat = 0; mat < 3; ++mat) {
    const ushort_t* wp = wb + (size_t)(1 + mat) * 65536;
    const float* wf = (mat == 0) ? Wqf : (mat == 1) ? Wkf : Wvf;
    const float* bb = (mat == 0) ? bq : (mat == 1) ? bk : bv;
    f32x4 acc[2][4];
#pragma unroll
    for (int a = 0; a < 2; ++a)
#pragma unroll
      for (int b = 0; b < 4; ++b) acc[a][b] = (f32x4){0.f,0.f,0.f,0.f};
#pragma unroll
    for (int ks = 0; ks < 8; ++ks) {
      short8 bf[4];
#pragma unroll
      for (int nf = 0; nf < 4; ++nf) {
        int off = (colbase + nf * 16 + li) * 256 + ks * 32 + g * 8;
        bf[nf] = WB ? *(const short8*)(wp + off) : cvt8(wf + off);
      }
      short8 af[2];
#pragma unroll
      for (int mt = 0; mt < 2; ++mt)
        af[mt] = *(const short8*)&sX[(mt * 16 + li) * 264 + ks * 32 + g * 8];
#pragma unroll
      for (int nf = 0; nf < 4; ++nf)
#pragma unroll
        for (int mt = 0; mt < 2; ++mt)
          acc[mt][nf] = MFMA_BF16(af[mt], bf[nf], acc[mt][nf]);
    }
#pragma unroll
    for (int nf = 0; nf < 4; ++nf) {
      int col = colbase + nf * 16 + li;
      float b = bb[col];
#pragma unroll
      for (int mt = 0; mt < 2; ++mt)
#pragma unroll
        for (int r = 0; r < 4; ++r) {
          float vv = acc[mt][nf][r] + b;
          int row = mt * 16 + g * 4 + r;
          if (mat == 0)      sQ[row * 264 + col] = f2bf(vv * 0.125f);  // 1/sqrt(64)
          else if (mat == 1) sK[row * 264 + col] = f2bf(vv);
          else               sVT[col * 40 + row] = f2bf(vv);
        }
    }
  }
  __syncthreads();   // barrier: QKV complete; sX(ex) and sPX(x-stage) now dead

  // -------- phase 3: per-head attention (head = wave)
  {
    f32x4 sc[2][2];
#pragma unroll
    for (int a = 0; a < 2; ++a)
#pragma unroll
      for (int b = 0; b < 2; ++b) sc[a][b] = (f32x4){0.f,0.f,0.f,0.f};
#pragma unroll
    for (int ks = 0; ks < 2; ++ks) {
      short8 afq[2], bfk[2];
#pragma unroll
      for (int t = 0; t < 2; ++t) {
        afq[t] = *(const short8*)&sQ[(t * 16 + li) * 264 + colbase + ks * 32 + g * 8];
        bfk[t] = *(const short8*)&sK[(t * 16 + li) * 264 + colbase + ks * 32 + g * 8];
      }
#pragma unroll
      for (int mt = 0; mt < 2; ++mt)
#pragma unroll
        for (int nt = 0; nt < 2; ++nt)
          sc[mt][nt] = MFMA_BF16(afq[mt], bfk[nt], sc[mt][nt]);
    }
    // mask + per-row softmax (row = mt*16+g*4+r, key = nt*16+li); q pre-scaled
#pragma unroll
    for (int mt = 0; mt < 2; ++mt) {
#pragma unroll
      for (int nt = 0; nt < 2; ++nt) {
        bool ok = (nt * 16 + li) < dg;
#pragma unroll
        for (int r = 0; r < 4; ++r) sc[mt][nt][r] = ok ? sc[mt][nt][r] : -1e30f;
      }
#pragma unroll
      for (int r = 0; r < 4; ++r) {
        float mx = fmaxf(sc[mt][0][r], sc[mt][1][r]);
#pragma unroll
        for (int d = 1; d < 16; d <<= 1) mx = fmaxf(mx, __shfl_xor(mx, d));
        float s0 = expf(sc[mt][0][r] - mx);
        float s1 = expf(sc[mt][1][r] - mx);
        float sum = s0 + s1;
#pragma unroll
        for (int d = 1; d < 16; d <<= 1) sum += __shfl_xor(sum, d);
        float inv = 1.0f / sum;
        sc[mt][0][r] = s0 * inv;
        sc[mt][1][r] = s1 * inv;
      }
    }
    // P -> per-wave LDS tile (bf16), then A-fragments
    ushort_t* Pb = &sPX[w * 1152];                    // 32x36
#pragma unroll
    for (int mt = 0; mt < 2; ++mt)
#pragma unroll
      for (int nt = 0; nt < 2; ++nt)
#pragma unroll
        for (int r = 0; r < 4; ++r)
          Pb[(mt * 16 + g * 4 + r) * 36 + nt * 16 + li] = f2bf(sc[mt][nt][r]);
    short8 pa[2];
#pragma unroll
    for (int mt = 0; mt < 2; ++mt) {
      const ushort_t* pr = &Pb[(mt * 16 + li) * 36 + g * 8];
      pa[mt] = pack2(*(const short4_t*)pr, *(const short4_t*)(pr + 4));
    }
    // PV
    f32x4 o[2][4];
#pragma unroll
    for (int a = 0; a < 2; ++a)
#pragma unroll
      for (int b = 0; b < 4; ++b) o[a][b] = (f32x4){0.f,0.f,0.f,0.f};
#pragma unroll
    for (int nf = 0; nf < 4; ++nf) {
      const ushort_t* vp = &sVT[(colbase + nf * 16 + li) * 40 + g * 8];
      short8 bfr = pack2(*(const short4_t*)vp, *(const short4_t*)(vp + 4));
#pragma unroll
      for (int mt = 0; mt < 2; ++mt) o[mt][nf] = MFMA_BF16(pa[mt], bfr, o[mt][nf]);
    }
    // attn-out overlays sX (each wave writes only its own cols)
#pragma unroll
    for (int mt = 0; mt < 2; ++mt)
#pragma unroll
      for (int nf = 0; nf < 4; ++nf)
#pragma unroll
        for (int r = 0; r < 4; ++r)
          sX[(mt * 16 + g * 4 + r) * 264 + colbase + nf * 16 + li] = f2bf(o[mt][nf][r]);
  }
  __syncthreads();   // barrier: attn-out complete

  // -------- phase 4: Wo GEMM + gelu + group softmax over logits + scatter
  {
    const ushort_t* wp = wb + (size_t)4 * 65536;
    f32x4 acc[2][4];
#pragma unroll
    for (int a = 0; a < 2; ++a)
#pragma unroll
      for (int b = 0; b < 4; ++b) acc[a][b] = (f32x4){0.f,0.f,0.f,0.f};
#pragma unroll
    for (int ks = 0; ks < 8; ++ks) {
      short8 bf[4];
#pragma unroll
      for (int nf = 0; nf < 4; ++nf) {
        int off = (colbase + nf * 16 + li) * 256 + ks * 32 + g * 8;
        bf[nf] = WB ? *(const short8*)(wp + off) : cvt8(Wof + off);
      }
      short8 af[2];
#pragma unroll
      for (int mt = 0; mt < 2; ++mt)
        af[mt] = *(const short8*)&sX[(mt * 16 + li) * 264 + ks * 32 + g * 8];
#pragma unroll
      for (int nf = 0; nf < 4; ++nf)
#pragma unroll
        for (int mt = 0; mt < 2; ++mt)
          acc[mt][nf] = MFMA_BF16(af[mt], bf[nf], acc[mt][nf]);
    }
    // gelu in place
#pragma unroll
    for (int nf = 0; nf < 4; ++nf) {
      float b = bo[colbase + nf * 16 + li];
#pragma unroll
      for (int mt = 0; mt < 2; ++mt)
#pragma unroll
        for (int r = 0; r < 4; ++r) acc[mt][nf][r] = gelu_f(acc[mt][nf][r] + b);
    }
    // logits for head w: mean of gate cols (nf 2,3), reduce over li
    float lp[2][4];
#pragma unroll
    for (int mt = 0; mt < 2; ++mt)
#pragma unroll
      for (int r = 0; r < 4; ++r) lp[mt][r] = acc[mt][2][r] + acc[mt][3][r];
#pragma unroll
    for (int d = 1; d < 16; d <<= 1)
#pragma unroll
      for (int mt = 0; mt < 2; ++mt)
#pragma unroll
        for (int r = 0; r < 4; ++r) lp[mt][r] += __shfl_xor(lp[mt][r], d);
    // group softmax over rows (each lane holds rows {mt*16+g*4+r}; reduce over g)
    float ml[2][4], mx = -1e30f;
#pragma unroll
    for (int mt = 0; mt < 2; ++mt)
#pragma unroll
      for (int r = 0; r < 4; ++r) {
        int rin = mt * 16 + g * 4 + r;
        ml[mt][r] = (rin < dg) ? lp[mt][r] * (1.f / 32.f) : -1e30f;
        mx = fmaxf(mx, ml[mt][r]);
      }
    mx = fmaxf(mx, __shfl_xor(mx, 16));
    mx = fmaxf(mx, __shfl_xor(mx, 32));
    float ee[2][4], ss = 0.f;
#pragma unroll
    for (int mt = 0; mt < 2; ++mt)
#pragma unroll
      for (int r = 0; r < 4; ++r) {
        int rin = mt * 16 + g * 4 + r;
        ee[mt][r] = (rin < dg) ? expf(ml[mt][r] - mx) : 0.f;
        ss += ee[mt][r];
      }
    ss += __shfl_xor(ss, 16);
    ss += __shfl_xor(ss, 32);
    float inv = 1.0f / ss;
#pragma unroll
    for (int mt = 0; mt < 2; ++mt)
#pragma unroll
      for (int r = 0; r < 4; ++r) {
        int rin = mt * 16 + g * 4 + r;
        if (rin < dg) {
          int eo = e1[st + rin];
          float a = ee[mt][r] * inv;
          atomicAdd(&dout[(size_t)eo * 128 + w * 32 + li],      acc[mt][0][r] * a);
          atomicAdd(&dout[(size_t)eo * 128 + w * 32 + 16 + li], acc[mt][1][r] * a);
        }
      }
  }
}

// ---------------------------------------------------------------- launch
extern "C" void kernel_launch(void* const* d_in, const int* in_sizes, int n_in,
                              void* d_out, int out_size, void* d_ws, size_t ws_size,
                              hipStream_t stream) {
  (void)n_in;
  const float* x  = (const float*)d_in[0];
  const float* Wc = (const float*)d_in[1];
  const float* bc = (const float*)d_in[2];
  const float* Wq = (const float*)d_in[3];
  const float* bq = (const float*)d_in[4];
  const float* Wk = (const float*)d_in[5];
  const float* bk = (const float*)d_in[6];
  const float* Wv = (const float*)d_in[7];
  const float* bv = (const float*)d_in[8];
  const float* Wo = (const float*)d_in[9];
  const float* bo = (const float*)d_in[10];
  const int* e0  = (const int*)d_in[11];
  const int* e1  = (const int*)d_in[12];
  const int* pos = (const int*)d_in[13];
  const int m = in_sizes[11];
  const int n = in_sizes[0] / 128;

  const size_t WBYTES = (size_t)5 * 65536 * sizeof(ushort_t);   // 640 KB
  const bool use_wb = ws_size >= WBYTES + (size_t)n * 2 * sizeof(int);

  ushort_t* wb = (ushort_t*)d_ws;
  int* startp = use_wb ? (int*)((char*)d_ws + WBYTES) : (int*)d_ws;
  int* degp = startp + n;

  hipMemsetAsync(d_out, 0, (size_t)out_size * sizeof(float), stream);
  hipMemsetAsync(startp, 0, (size_t)n * 2 * sizeof(int), stream);

  k_prep<<<(m + 255) / 256, 256, 0, stream>>>(e0, pos, m, startp, degp);
  if (use_wb) {
    k_wcvt<<<(5 * 65536 + 255) / 256, 256, 0, stream>>>(Wc, Wq, Wk, Wv, Wo, wb);
    k_fused3<true><<<n, 256, 0, stream>>>(x, wb, Wc, bc, Wq, bq, Wk, bk, Wv, bv, Wo, bo,
                                          e1, startp, degp, (float*)d_out, m, n);
  } else {
    k_fused3<false><<<n, 256, 0, stream>>>(x, nullptr, Wc, bc, Wq, bq, Wk, bk, Wv, bv, Wo, bo,
                                           e1, startp, degp, (float*)d_out, m, n);
  }
}